// Round 2
// baseline (221.124 us; speedup 1.0000x reference)
//
#include <hip/hip_runtime.h>
#include <math.h>

#define B_ 16
#define N_ 128
#define H_ 768
#define NEGV (-1e9f)
#define CFAC 2.8853900817779268f   // 2/ln(2): exp2(CFAC*x) == exp(2x)

// ---------------- ws layout (float offsets) ----------------
// eq      : 0         (B*N*H = 1572864)   exp2(CFAC*(dec@Wq+bq))
// ek      : 1572864   (1572864)           exp2(CFAC*(sen@Wk+bk))
// sc      : 3145728   (B*N*N = 262144)    scores (only t<len, j<len tiles valid)
// inv     : 3407872   (2048, int)         inverse permutation of target
// w2      : 3409920   (768)               -2*wt
// sumwt   : 3410688   (1)                 sum(wt)
// rowterm : 3410692   (2048)
// colterm : 3412740   (2048)

__device__ __forceinline__ float wave_sum(float v) {
    #pragma unroll
    for (int o = 32; o > 0; o >>= 1) v += __shfl_down(v, o);
    return v;
}
__device__ __forceinline__ float wave_max(float v) {
    #pragma unroll
    for (int o = 32; o > 0; o >>= 1) v = fmaxf(v, __shfl_down(v, o));
    return v;
}

// ---------------- GEMM (+ fused exp2 epilogue) + prep lane ----------------
// z=0: eq = exp2(CFAC*(dec@Wq+bq)); z=1: ek = exp2(CFAC*(sen@Wk+bk)); z=2: prep
// tile 128x96, micro 8x6, BK=16, 256 threads. grid (16, 8, 3)
__global__ __launch_bounds__(256) void gemm_kernel(const float* __restrict__ dec,
                                                   const float* __restrict__ sen,
                                                   const float* __restrict__ Wq,
                                                   const float* __restrict__ bq,
                                                   const float* __restrict__ Wk,
                                                   const float* __restrict__ bk,
                                                   const float* __restrict__ wt,
                                                   const int* __restrict__ target,
                                                   float* __restrict__ eq,
                                                   float* __restrict__ ek,
                                                   int* __restrict__ inv,
                                                   float* __restrict__ w2,
                                                   float* __restrict__ sumwt) {
    const int tid = threadIdx.x;

    if (blockIdx.z == 2) {
        // prep: inverse permutation (p<16), w2/sumwt (p==16)
        const int p = blockIdx.x + 16 * blockIdx.y;
        if (p < B_) {
            if (tid < N_) inv[p * N_ + target[p * N_ + tid]] = tid;
        } else if (p == B_) {
            __shared__ float red[4];
            float local = 0.f;
            for (int h = tid; h < H_; h += 256) {
                float w = wt[h];
                w2[h] = -2.f * w;
                local += w;
            }
            float v = wave_sum(local);
            if ((tid & 63) == 0) red[tid >> 6] = v;
            __syncthreads();
            if (tid == 0) sumwt[0] = red[0] + red[1] + red[2] + red[3];
        }
        return;
    }

    const float* A; const float* W; const float* bias; float* out;
    if (blockIdx.z == 0) { A = dec; W = Wq; bias = bq; out = eq; }
    else                 { A = sen; W = Wk; bias = bk; out = ek; }

    const int m0 = blockIdx.x * 128;
    const int n0 = blockIdx.y * 96;
    const int tx = tid & 15;       // 6 cols each
    const int ty = tid >> 4;       // 8 rows each

    __shared__ __align__(16) float As[16][132];  // [k][m], padded
    __shared__ __align__(16) float Bs[16][100];  // [k][n], padded

    float acc[8][6];
    #pragma unroll
    for (int r = 0; r < 8; r++)
        #pragma unroll
        for (int c = 0; c < 6; c++) acc[r][c] = 0.f;

    const int ra = tid >> 1;          // 0..127 A-row
    const int kc = (tid & 1) * 8;     // k offset
    const int r1 = tid / 24,        c1 = tid % 24;         // B float4 #tid
    const int r2 = (256 + tid) / 24, c2 = (256 + tid) % 24; // B float4 #256+tid

    for (int k0 = 0; k0 < H_; k0 += 16) {
        float4 a0 = *(const float4*)&A[(m0 + ra) * H_ + k0 + kc];
        float4 a1 = *(const float4*)&A[(m0 + ra) * H_ + k0 + kc + 4];
        float4 b0 = *(const float4*)&W[(k0 + r1) * H_ + n0 + c1 * 4];
        float4 b1;
        if (tid < 128) b1 = *(const float4*)&W[(k0 + r2) * H_ + n0 + c2 * 4];
        __syncthreads();
        As[kc + 0][ra] = a0.x; As[kc + 1][ra] = a0.y;
        As[kc + 2][ra] = a0.z; As[kc + 3][ra] = a0.w;
        As[kc + 4][ra] = a1.x; As[kc + 5][ra] = a1.y;
        As[kc + 6][ra] = a1.z; As[kc + 7][ra] = a1.w;
        *(float4*)&Bs[r1][c1 * 4] = b0;
        if (tid < 128) *(float4*)&Bs[r2][c2 * 4] = b1;
        __syncthreads();
        #pragma unroll
        for (int k = 0; k < 16; k++) {
            float4 a0_ = *(const float4*)&As[k][ty * 8];
            float4 a1_ = *(const float4*)&As[k][ty * 8 + 4];
            float2 bb0 = *(const float2*)&Bs[k][tx * 6];
            float2 bb1 = *(const float2*)&Bs[k][tx * 6 + 2];
            float2 bb2 = *(const float2*)&Bs[k][tx * 6 + 4];
            float av[8] = {a0_.x, a0_.y, a0_.z, a0_.w, a1_.x, a1_.y, a1_.z, a1_.w};
            float bv[6] = {bb0.x, bb0.y, bb1.x, bb1.y, bb2.x, bb2.y};
            #pragma unroll
            for (int r = 0; r < 8; r++)
                #pragma unroll
                for (int c = 0; c < 6; c++)
                    acc[r][c] = fmaf(av[r], bv[c], acc[r][c]);
        }
    }

    float bvv[6];
    #pragma unroll
    for (int c = 0; c < 6; c++) bvv[c] = bias[n0 + tx * 6 + c];
    #pragma unroll
    for (int r = 0; r < 8; r++) {
        float e[6];
        #pragma unroll
        for (int c = 0; c < 6; c++)
            e[c] = __builtin_amdgcn_exp2f(CFAC * (acc[r][c] + bvv[c]));
        float* dst = &out[(m0 + ty * 8 + r) * H_ + n0 + tx * 6];
        *(float2*)&dst[0] = make_float2(e[0], e[1]);
        *(float2*)&dst[2] = make_float2(e[2], e[3]);
        *(float2*)&dst[4] = make_float2(e[4], e[5]);
    }
}

// ---------------- scores: sc[b,t,j] = base + sum_h w2[h]*rcp(1 + eq*ek) ----------------
// tile 16x16, 256 threads, grid (8, 8, 16); skip tiles with t0>=len or j0>=len
__global__ __launch_bounds__(256) void scores_kernel(const float* __restrict__ eq,
                                                     const float* __restrict__ ek,
                                                     const float* __restrict__ w2,
                                                     const float* __restrict__ sumwt,
                                                     const float* __restrict__ bt,
                                                     const int* __restrict__ tgt_len,
                                                     float* __restrict__ sc) {
    const int b  = blockIdx.z;
    const int t0 = blockIdx.y * 16;
    const int j0 = blockIdx.x * 16;
    const int len = tgt_len[b];
    if (t0 >= len || j0 >= len) return;   // masked before every read downstream

    const int tid = threadIdx.x;
    const int jx = tid & 15;
    const int ty = tid >> 4;
    const int r  = tid >> 4;
    const int sg = tid & 15;

    __shared__ __align__(16) float qs[16][68];
    __shared__ __align__(16) float ks[16][68];
    __shared__ __align__(16) float w2s[64];

    float acc0 = 0.f, acc1 = 0.f, acc2 = 0.f, acc3 = 0.f;

    for (int h0 = 0; h0 < H_; h0 += 64) {
        float4 qv = *(const float4*)&eq[(b * N_ + t0 + r) * H_ + h0 + sg * 4];
        float4 kv = *(const float4*)&ek[(b * N_ + j0 + r) * H_ + h0 + sg * 4];
        float4 wv;
        if (tid < 16) wv = *(const float4*)&w2[h0 + tid * 4];
        __syncthreads();
        *(float4*)&qs[r][sg * 4] = qv;
        *(float4*)&ks[r][sg * 4] = kv;
        if (tid < 16) *(float4*)&w2s[tid * 4] = wv;
        __syncthreads();
        #pragma unroll
        for (int hh = 0; hh < 64; hh += 4) {
            float4 q4 = *(const float4*)&qs[ty][hh];
            float4 k4 = *(const float4*)&ks[jx][hh];
            float4 w4 = *(const float4*)&w2s[hh];
            acc0 = fmaf(w4.x, __builtin_amdgcn_rcpf(fmaf(q4.x, k4.x, 1.f)), acc0);
            acc1 = fmaf(w4.y, __builtin_amdgcn_rcpf(fmaf(q4.y, k4.y, 1.f)), acc1);
            acc2 = fmaf(w4.z, __builtin_amdgcn_rcpf(fmaf(q4.z, k4.z, 1.f)), acc2);
            acc3 = fmaf(w4.w, __builtin_amdgcn_rcpf(fmaf(q4.w, k4.w, 1.f)), acc3);
        }
        __syncthreads();
    }
    float base = sumwt[0] + bt[0];
    float accv = (acc0 + acc1) + (acc2 + acc3);
    sc[(b * N_ + t0 + ty) * N_ + j0 + jx] = accv + base;
}

// ---------------- fused row/col loss terms (z=0 row, z=1 col) ----------------
// NOTE cancellation order: shifted = es[idx] - m FIRST (matches jax log_softmax),
// then nll = log(sum) - shifted. Gets the -1e9-absorption cases bit-exact.
__global__ __launch_bounds__(128) void loss_kernel(const float* __restrict__ sc,
                                                   const int* __restrict__ inv,
                                                   const int* __restrict__ target,
                                                   const int* __restrict__ tgt_len,
                                                   float* __restrict__ rowterm,
                                                   float* __restrict__ colterm) {
    const int b = blockIdx.y;
    const int len = tgt_len[b];
    __shared__ float es[128];
    __shared__ float red[2];

    if (blockIdx.z == 0) {
        const int t = blockIdx.x, j = threadIdx.x;
        float s = sc[(b * N_ + t) * N_ + j];           // poison reads are masked below
        int invj = inv[b * N_ + j];
        float e = (invj < t || j >= len) ? NEGV : s;
        es[j] = e;
        float v = wave_max(e);
        if ((j & 63) == 0) red[j >> 6] = v;
        __syncthreads();
        float m = fmaxf(red[0], red[1]);
        __syncthreads();
        float p = __expf(e - m);
        float ps = wave_sum(p);
        if ((j & 63) == 0) red[j >> 6] = ps;
        __syncthreads();
        if (j == 0) {
            float sum = red[0] + red[1];
            int jt = target[b * N_ + t];
            float shifted = es[jt] - m;
            rowterm[b * N_ + t] = (t < len) ? (__logf(sum) - shifted) : 0.f;
        }
    } else {
        const int j = blockIdx.x, t = threadIdx.x;
        float s = sc[(b * N_ + t) * N_ + j];
        float e = (t < len && j < len) ? s : NEGV;
        es[t] = e;
        float v = wave_max(e);
        if ((t & 63) == 0) red[t >> 6] = v;
        __syncthreads();
        float m = fmaxf(red[0], red[1]);
        __syncthreads();
        float p = __expf(e - m);
        float ps = wave_sum(p);
        if ((t & 63) == 0) red[t >> 6] = ps;
        __syncthreads();
        if (t == 0) {
            float sum = red[0] + red[1];
            int ts = inv[b * N_ + j];                  // row where target==j
            float shifted = es[ts] - m;
            colterm[b * N_ + ts] = (ts < len) ? (__logf(sum) - shifted) : 0.f;
        }
    }
}

// ---------------- final reduction ----------------
__global__ __launch_bounds__(128) void final_kernel(const float* __restrict__ rowterm,
                                                    const float* __restrict__ colterm,
                                                    const int* __restrict__ tgt_len,
                                                    float* __restrict__ out) {
    const int tid = threadIdx.x;
    __shared__ float red[2];
    float rowacc = 0.f, colacc = 0.f;
    for (int b = 0; b < B_; b++) {
        float r = rowterm[b * N_ + tid];
        float c = colterm[b * N_ + tid];
        float v = wave_sum(r);
        if ((tid & 63) == 0) red[tid >> 6] = v;
        __syncthreads();
        float rs = red[0] + red[1];
        __syncthreads();
        float w = wave_sum(c);
        if ((tid & 63) == 0) red[tid >> 6] = w;
        __syncthreads();
        float cs = red[0] + red[1];
        __syncthreads();
        if (tid == 0) {
            float lenf = (float)tgt_len[b];
            rowacc += rs / (lenf - 1.f);
            colacc += cs / (lenf * (lenf - 1.f));
        }
    }
    if (tid == 0) out[0] = rowacc / (float)B_ + colacc / (float)B_;
}

extern "C" void kernel_launch(void* const* d_in, const int* in_sizes, int n_in,
                              void* d_out, int out_size, void* d_ws, size_t ws_size,
                              hipStream_t stream) {
    (void)in_sizes; (void)n_in; (void)out_size; (void)ws_size;
    const float* dec = (const float*)d_in[0];
    const float* sen = (const float*)d_in[1];
    const float* Wq  = (const float*)d_in[2];
    const float* bq  = (const float*)d_in[3];
    const float* Wk  = (const float*)d_in[4];
    const float* bk  = (const float*)d_in[5];
    const float* wt  = (const float*)d_in[6];
    const float* bt  = (const float*)d_in[7];
    const int* target  = (const int*)d_in[8];
    const int* tgt_len = (const int*)d_in[9];

    float* ws = (float*)d_ws;
    float* eq      = ws;
    float* ek      = ws + 1572864;
    float* sc      = ws + 3145728;
    int*   inv     = (int*)(ws + 3407872);
    float* w2      = ws + 3409920;
    float* sumwt   = ws + 3410688;
    float* rowterm = ws + 3410692;
    float* colterm = ws + 3412740;
    float* out = (float*)d_out;

    gemm_kernel<<<dim3(16, 8, 3), 256, 0, stream>>>(dec, sen, Wq, bq, Wk, bk, wt,
                                                    target, eq, ek, inv, w2, sumwt);
    scores_kernel<<<dim3(8, 8, 16), 256, 0, stream>>>(eq, ek, w2, sumwt, bt, tgt_len, sc);
    loss_kernel<<<dim3(N_, B_, 2), 128, 0, stream>>>(sc, inv, target, tgt_len, rowterm, colterm);
    final_kernel<<<1, 128, 0, stream>>>(rowterm, colterm, tgt_len, out);
}